// Round 3
// baseline (63.021 us; speedup 1.0000x reference)
//
#include <hip/hip_runtime.h>
#include <math.h>

namespace {

constexpr int NCH   = 32;     // channels
constexpr int NG    = 2048;   // grid points
constexpr int BATCH = 32;
constexpr float DXC = 0.08f;

constexpr int NSEG   = 16;            // output segments per row (blocks per b)
constexpr int SEGLEN = NG / NSEG;     // 128 m-values per block
constexpr int NCHUNK = 32;            // chunks over the full row
constexpr int CHL    = NG / NCHUNK;   // 64 elements per chunk
constexpr int NSUB   = 8;             // subchunks per chunk
constexpr int SUBL   = CHL / NSUB;    // 8 elements per subchunk
constexpr int CPS    = NCHUNK / NSEG; // chunks per segment = 2
constexpr int NT     = 16;            // chunk-thread groups per block

// out[b,m,c] = s_c * (F[m] + G[m] - x[m])
//   F[m] = x[m] + r_c F[m-1], G[m] = x[m] + r_c G[m+1]
//   r_c = exp(-DX/w_c), s_c = DX/(2 w_c), w_c = 0.1 + 4.9*sigmoid(eta_c)
// 512 blocks (b x 16 seg) of 512 threads -> 2 blocks/CU so barrier drains and
// cold global loads of one block overlap the other block's compute.
__global__ __launch_bounds__(512, 4)
void egc_kernel(const float* __restrict__ inputs,
                const float* __restrict__ eta,
                float* __restrict__ out) {
    __shared__ float xs[NG];                 // 8 KB: full input row
    __shared__ float pw[64][NCH];            // 8 KB: r^i per channel
    __shared__ float F8[CPS][NSUB][NCH];     // 2 KB: local fwd scan @ subchunk ends (own segment)
    __shared__ float G8[CPS][NSUB][NCH];     // 2 KB: local bwd scan @ subchunk starts (own segment)
    __shared__ float Ef[NCHUNK][NCH];        // 4 KB: per-chunk total fwd carry
    __shared__ float Eb[NCHUNK][NCH];        // 4 KB: per-chunk total bwd carry
    __shared__ float CF[NCHUNK][NCH];        // 4 KB: full F entering chunk
    __shared__ float CB[NCHUNK][NCH];        // 4 KB: full G just past chunk end

    const int tid = threadIdx.x;
    const int c   = tid & 31;        // channel (fast index -> conflict-free LDS, coalesced writes)
    const int t   = tid >> 5;        // chunk-thread group [0,16)
    const int b   = blockIdx.x >> 4;
    const int seg = blockIdx.x & (NSEG - 1);

    // per-channel parameters
    const float e   = eta[c];
    const float w   = 0.1f + 4.9f / (1.0f + expf(-e));
    const float lam = DXC / w;
    const float s   = 0.5f * DXC / w;

    // ---- phase 0: stage input row (float4) + power table ----
    const float* xrow = inputs + (size_t)b * NG;
    reinterpret_cast<float4*>(xs)[tid] = reinterpret_cast<const float4*>(xrow)[tid];
    pw[t][c]      = expf(-lam * (float)t);
    pw[t + 16][c] = expf(-lam * (float)(t + 16));
    pw[t + 32][c] = expf(-lam * (float)(t + 32));
    pw[t + 48][c] = expf(-lam * (float)(t + 48));
    __syncthreads();

    // per-thread copies of small powers (broadcast reads, conflict-free)
    float p[SUBL];
#pragma unroll
    for (int i = 0; i < SUBL; ++i) p[i] = pw[i][c];
    const float r  = p[1];
    const float p8 = pw[SUBL][c];                 // r^8

    // ---- phase 1: thread t scans chunks {2t, 2t+1} (8-FMA sub-chains + r^8 folds) ----
    const bool own = (t == seg);                  // this thread's chunks are the segment's chunks
#pragma unroll
    for (int kk = 0; kk < CPS; ++kk) {
        const int base = (2 * t + kk) * CHL;
        float sf[NSUB], sb[NSUB];
#pragma unroll
        for (int ss = 0; ss < NSUB; ++ss) {
            const int o = base + ss * SUBL;
            float xv[SUBL];
#pragma unroll
            for (int i = 0; i < SUBL; ++i) xv[i] = xs[o + i];
            float f = 0.0f, g = 0.0f;
#pragma unroll
            for (int i = 0; i < SUBL; ++i) {
                f = fmaf(p[SUBL - 1 - i], xv[i], f);   // sum x[i] * r^(7-i)
                g = fmaf(p[i],            xv[i], g);   // sum x[i] * r^i
            }
            sf[ss] = f; sb[ss] = g;
        }
        float fa = 0.0f;
#pragma unroll
        for (int ss = 0; ss < NSUB; ++ss) {
            fa = fmaf(p8, fa, sf[ss]);
            if (own) F8[kk][ss][c] = fa;
        }
        float ga = 0.0f;
#pragma unroll
        for (int ss = NSUB - 1; ss >= 0; --ss) {
            ga = fmaf(p8, ga, sb[ss]);
            if (own) G8[kk][ss][c] = ga;
        }
        Ef[2 * t + kk][c] = fa;
        Eb[2 * t + kk][c] = ga;
    }
    __syncthreads();

    // ---- phase 2: chunk-level carry scans, prefetched + fully unrolled ----
    {
        const float p32 = pw[32][c];
        const float rho = p32 * p32;                 // r^64
        if (t == 0) {                                // wave 0, lanes 0..31
            float ev[NCHUNK];
#pragma unroll
            for (int k = 0; k < NCHUNK; ++k) ev[k] = Ef[k][c];
            float fe = 0.0f;
#pragma unroll
            for (int k = 0; k < NCHUNK; ++k) { CF[k][c] = fe; fe = fmaf(rho, fe, ev[k]); }
        } else if (t == 2) {                         // wave 1, lanes 0..31
            float ev[NCHUNK];
#pragma unroll
            for (int k = 0; k < NCHUNK; ++k) ev[k] = Eb[k][c];
            float ge = 0.0f;
#pragma unroll
            for (int k = NCHUNK - 1; k >= 0; --k) { CB[k][c] = ge; ge = fmaf(rho, ge, ev[k]); }
        }
    }
    __syncthreads();

    // ---- phase 3: finalize 8 outputs of subchunk T = seg*16 + t ----
    const int T     = seg * NT + t;
    const int chunk = T >> 3;                        // = 2*seg + (t>>3)
    const int sub   = T & (NSUB - 1);
    const int tc    = t >> 3;                        // 0 or 1
    const int m0    = T * SUBL;

    float fin = CF[chunk][c] * pw[SUBL * sub][c];
    if (sub > 0) fin += F8[tc][sub - 1][c];
    float gin;
    if (sub < NSUB - 1)
        gin = fmaf(CB[chunk][c], pw[CHL - SUBL * (sub + 1)][c], G8[tc][sub + 1][c]);
    else
        gin = CB[chunk][c];

    float xv[SUBL], Fv[SUBL];
#pragma unroll
    for (int i = 0; i < SUBL; ++i) xv[i] = xs[m0 + i];

    float f = fin;
#pragma unroll
    for (int i = 0; i < SUBL; ++i) { f = fmaf(r, f, xv[i]); Fv[i] = f; }

    float g = gin;
    float* orow = out + ((size_t)b * NG + m0) * NCH + c;
#pragma unroll
    for (int i = SUBL - 1; i >= 0; --i) {
        g = fmaf(r, g, xv[i]);
        orow[(size_t)i * NCH] = s * (Fv[i] + g - xv[i]);
    }
}

} // namespace

extern "C" void kernel_launch(void* const* d_in, const int* in_sizes, int n_in,
                              void* d_out, int out_size, void* d_ws, size_t ws_size,
                              hipStream_t stream) {
    const float* inputs = (const float*)d_in[0];
    // d_in[1] = grids (uniform spacing DX; |x_n - x_m| = |n-m|*DX, so unused)
    const float* eta    = (const float*)d_in[2];
    float* out          = (float*)d_out;

    dim3 grid(BATCH * NSEG);   // 512 blocks: (b, segment) -> 2 blocks/CU
    dim3 block(512);           // (32 channels) x (16 chunk-thread groups)
    hipLaunchKernelGGL(egc_kernel, grid, block, 0, stream, inputs, eta, out);
}